// Round 13
// baseline (90.398 us; speedup 1.0000x reference)
//
#include <hip/hip_runtime.h>

#define Bn 1024
#define Dn 512
#define Cn 512
#define Sn 8            // samples per block
#define NT 512          // 8 waves
#define NBLK (Bn / Sn)  // 128 blocks -> 1 block/CU on 128 CUs, no W redundancy per thread

__device__ __forceinline__ float waveSum(float v) {
    #pragma unroll
    for (int off = 32; off > 0; off >>= 1) v += __shfl_xor(v, off, 64);
    return v;
}
__device__ __forceinline__ float waveMax(float v) {
    #pragma unroll
    for (int off = 32; off > 0; off >>= 1) v = fmaxf(v, __shfl_xor(v, off, 64));
    return v;
}

// Single launch, no cross-block deps. Thread owns column c=tid for 8 samples.
// x lives transposed in LDS (64B rows) -> 2 broadcast ds_read_b128 per k serve all lanes.
// W read coalesced 4B/lane (256B/wave, full 2KB row per block), K-unroll 16 for MLP.
__global__ __launch_bounds__(NT) void gnorm_one(
    const float* __restrict__ x,     // [B][D]
    const float* __restrict__ y,     // [B][C]
    const float* __restrict__ W,     // [D][C]
    const float* __restrict__ bias,  // [C]
    float* __restrict__ out)         // [B]
{
    __shared__ float xt[Dn][16];     // x transposed, row stride 64B (16B-aligned), 32 KB
    __shared__ float red[Sn][8];     // [sample][wave] cross-wave reduce
    __shared__ float xn2s[Sn];

    const int tid = threadIdx.x;
    const int wv  = tid >> 6;        // 0..7
    const int l   = tid & 63;
    const int s0  = blockIdx.x * Sn;

    // ---- stage x transposed: thread -> sample s=tid&7, k-range (tid>>3)*8..+8 ----
    {
        const int s  = tid & 7;
        const int k0 = (tid >> 3) * 8;
        const float* xp = &x[(size_t)(s0 + s) * Dn + k0];
        float4 a = *(const float4*)xp;
        float4 b = *(const float4*)(xp + 4);
        xt[k0 + 0][s] = a.x; xt[k0 + 1][s] = a.y; xt[k0 + 2][s] = a.z; xt[k0 + 3][s] = a.w;
        xt[k0 + 4][s] = b.x; xt[k0 + 5][s] = b.y; xt[k0 + 6][s] = b.z; xt[k0 + 7][s] = b.w;
    }
    // ---- ||x||^2: wave wv owns sample wv (coalesced, fp32 exact; verified R9 pattern) ----
    {
        const float* xr = &x[(size_t)(s0 + wv) * Dn + l * 8];
        float4 a = *(const float4*)xr;
        float4 b = *(const float4*)(xr + 4);
        float ss = a.x*a.x + a.y*a.y + a.z*a.z + a.w*a.w
                 + b.x*b.x + b.y*b.y + b.z*b.z + b.w*b.w;
        ss = waveSum(ss);
        if (l == 0) xn2s[wv] = ss;
    }
    __syncthreads();

    // ---- main K-loop: c = tid, 8 samples, unroll 16 (W loads front-loaded) ----
    const int c = tid;
    const float* wp = &W[c];
    float acc[8] = {0.f, 0.f, 0.f, 0.f, 0.f, 0.f, 0.f, 0.f};

    for (int k = 0; k < Dn; k += 16) {
        float wr[16];
        #pragma unroll
        for (int i = 0; i < 16; ++i) wr[i] = wp[(size_t)(k + i) * Cn];
        #pragma unroll
        for (int i = 0; i < 16; ++i) {
            float4 xa = *(const float4*)&xt[k + i][0];   // broadcast (same addr all lanes)
            float4 xb = *(const float4*)&xt[k + i][4];
            acc[0] = fmaf(xa.x, wr[i], acc[0]);
            acc[1] = fmaf(xa.y, wr[i], acc[1]);
            acc[2] = fmaf(xa.z, wr[i], acc[2]);
            acc[3] = fmaf(xa.w, wr[i], acc[3]);
            acc[4] = fmaf(xb.x, wr[i], acc[4]);
            acc[5] = fmaf(xb.y, wr[i], acc[5]);
            acc[6] = fmaf(xb.z, wr[i], acc[6]);
            acc[7] = fmaf(xb.w, wr[i], acc[7]);
        }
    }

    // ---- epilogue: per-sample block-wide softmax stats + ||g||^2 ----
    const float bc = bias[c];
    float z[8];
    #pragma unroll
    for (int s = 0; s < 8; ++s) z[s] = acc[s] + bc;

    #pragma unroll
    for (int s = 0; s < 8; ++s) {
        float m = waveMax(z[s]);
        if (l == 0) red[s][wv] = m;
    }
    __syncthreads();
    float mx[8];
    #pragma unroll
    for (int s = 0; s < 8; ++s) {
        float m = red[s][0];
        #pragma unroll
        for (int w = 1; w < 8; ++w) m = fmaxf(m, red[s][w]);
        mx[s] = m;
    }
    __syncthreads();

    float e[8];
    #pragma unroll
    for (int s = 0; s < 8; ++s) {
        e[s] = __expf(z[s] - mx[s]);
        float sv = waveSum(e[s]);
        if (l == 0) red[s][wv] = sv;
    }
    __syncthreads();
    float inv[8];
    #pragma unroll
    for (int s = 0; s < 8; ++s) {
        float dv = red[s][0];
        #pragma unroll
        for (int w = 1; w < 8; ++w) dv += red[s][w];
        inv[s] = 1.0f / dv;
    }
    __syncthreads();

    #pragma unroll
    for (int s = 0; s < 8; ++s) {
        float g = e[s] * inv[s] - y[(size_t)(s0 + s) * Cn + c];
        float gs = waveSum(g * g);
        if (l == 0) red[s][wv] = gs;
    }
    __syncthreads();

    if (tid < Sn) {
        float gsq = red[tid][0];
        #pragma unroll
        for (int w = 1; w < 8; ++w) gsq += red[tid][w];
        // ||gW||_F^2 + ||gb||^2 = (||x||^2 + 1) * ||g||^2
        out[s0 + tid] = sqrtf((xn2s[tid] + 1.0f) * gsq);
    }
}

extern "C" void kernel_launch(void* const* d_in, const int* in_sizes, int n_in,
                              void* d_out, int out_size, void* d_ws, size_t ws_size,
                              hipStream_t stream) {
    const float* x  = (const float*)d_in[0];
    const float* y  = (const float*)d_in[1];
    const float* W  = (const float*)d_in[2];
    const float* b  = (const float*)d_in[3];
    float* out = (float*)d_out;
    gnorm_one<<<dim3(NBLK), dim3(NT), 0, stream>>>(x, y, W, b, out);
}

// Round 14
// 84.629 us; speedup vs baseline: 1.0682x; 1.0682x over previous
//
#include <hip/hip_runtime.h>

#define Bn 1024
#define Dn 512
#define Cn 512
#define Sn 4            // samples per block
#define NT 512          // 8 waves; thread owns one column
#define NBLK (Bn / Sn)  // 256 blocks -> 1 block/CU on all 256 CUs

__device__ __forceinline__ float waveSum(float v) {
    #pragma unroll
    for (int off = 32; off > 0; off >>= 1) v += __shfl_xor(v, off, 64);
    return v;
}
__device__ __forceinline__ float waveMax(float v) {
    #pragma unroll
    for (int off = 32; off > 0; off >>= 1) v = fmaxf(v, __shfl_xor(v, off, 64));
    return v;
}

// Single launch, no cross-block deps, no LDS in the hot loop.
// x is read via wave-uniform addresses -> scalar loads (SGPR broadcast, K$),
// W via coalesced 4B/lane vector loads (256B/wave), K-unroll 16 for MLP.
__global__ __launch_bounds__(NT) void gnorm_one(
    const float* __restrict__ x,     // [B][D]
    const float* __restrict__ y,     // [B][C]
    const float* __restrict__ W,     // [D][C]
    const float* __restrict__ bias,  // [C]
    float* __restrict__ out)         // [B]
{
    __shared__ float red[Sn][8];     // [sample][wave] cross-wave reduce
    __shared__ float xn2s[Sn];

    const int tid = threadIdx.x;
    const int wv  = tid >> 6;        // 0..7
    const int l   = tid & 63;
    const int s0  = blockIdx.x * Sn;

    // ---- ||x||^2: waves 0..3 own samples 0..3 (coalesced fp32, exact) ----
    if (wv < Sn) {
        const float* xr = &x[(size_t)(s0 + wv) * Dn + l * 8];
        float4 a = *(const float4*)xr;
        float4 b = *(const float4*)(xr + 4);
        float ss = a.x*a.x + a.y*a.y + a.z*a.z + a.w*a.w
                 + b.x*b.x + b.y*b.y + b.z*b.z + b.w*b.w;
        ss = waveSum(ss);
        if (l == 0) xn2s[wv] = ss;
    }

    // ---- main K-loop: c = tid, 4 samples, unroll 16 ----
    // x loads are wave-uniform -> s_load (scalar pipe); W loads coalesced vector.
    const int c = tid;
    const float* wp  = &W[c];
    const float* xr0 = &x[(size_t)s0 * Dn];   // block-uniform base
    float acc[4] = {0.f, 0.f, 0.f, 0.f};

    for (int k = 0; k < Dn; k += 16) {
        float wr[16];
        #pragma unroll
        for (int i = 0; i < 16; ++i) wr[i] = wp[(size_t)(k + i) * Cn];
        #pragma unroll
        for (int i = 0; i < 16; ++i) {
            #pragma unroll
            for (int s = 0; s < Sn; ++s)
                acc[s] = fmaf(xr0[(size_t)s * Dn + k + i], wr[i], acc[s]);
        }
    }

    // ---- epilogue: per-sample block-wide softmax stats + ||g||^2 ----
    const float bc = bias[c];
    float z[Sn];
    #pragma unroll
    for (int s = 0; s < Sn; ++s) z[s] = acc[s] + bc;

    __syncthreads();   // xn2s written; red about to be used
    #pragma unroll
    for (int s = 0; s < Sn; ++s) {
        float m = waveMax(z[s]);
        if (l == 0) red[s][wv] = m;
    }
    __syncthreads();
    float mx[Sn];
    #pragma unroll
    for (int s = 0; s < Sn; ++s) {
        float m = red[s][0];
        #pragma unroll
        for (int w = 1; w < 8; ++w) m = fmaxf(m, red[s][w]);
        mx[s] = m;
    }
    __syncthreads();

    float e[Sn];
    #pragma unroll
    for (int s = 0; s < Sn; ++s) {
        e[s] = __expf(z[s] - mx[s]);
        float sv = waveSum(e[s]);
        if (l == 0) red[s][wv] = sv;
    }
    __syncthreads();
    float inv[Sn];
    #pragma unroll
    for (int s = 0; s < Sn; ++s) {
        float dv = red[s][0];
        #pragma unroll
        for (int w = 1; w < 8; ++w) dv += red[s][w];
        inv[s] = 1.0f / dv;
    }
    __syncthreads();

    #pragma unroll
    for (int s = 0; s < Sn; ++s) {
        float g = e[s] * inv[s] - y[(size_t)(s0 + s) * Cn + c];
        float gs = waveSum(g * g);
        if (l == 0) red[s][wv] = gs;
    }
    __syncthreads();

    if (tid < Sn) {
        float gsq = red[tid][0];
        #pragma unroll
        for (int w = 1; w < 8; ++w) gsq += red[tid][w];
        // ||gW||_F^2 + ||gb||^2 = (||x||^2 + 1) * ||g||^2
        out[s0 + tid] = sqrtf((xn2s[tid] + 1.0f) * gsq);
    }
}

extern "C" void kernel_launch(void* const* d_in, const int* in_sizes, int n_in,
                              void* d_out, int out_size, void* d_ws, size_t ws_size,
                              hipStream_t stream) {
    const float* x  = (const float*)d_in[0];
    const float* y  = (const float*)d_in[1];
    const float* W  = (const float*)d_in[2];
    const float* b  = (const float*)d_in[3];
    float* out = (float*)d_out;
    gnorm_one<<<dim3(NBLK), dim3(NT), 0, stream>>>(x, y, W, b, out);
}